// Round 1
// 226.975 us; speedup vs baseline: 1.0112x; 1.0112x over previous
//
#include <hip/hip_runtime.h>

#define NK 512
#define ND 64
#define NHW 4096
#define NPIX 131072            // 32*64*64
#define OUT_ELEMS 8388608      // 32*64*64*64
#define XS 68                  // LDS x-row stride (floats), 272 B = 16B-aligned, bank-offset 4
#define CS 68                  // LDS chunk-row stride (floats)

// ---------------------------------------------------------------------------
// Prep: sc[k] = numpy-pairwise-8 fp32 sum of fl(c_d^2); zero the two loss
// slots (harness re-poisons d_out/d_ws to 0xAA before every timed replay).
// ---------------------------------------------------------------------------
__global__ __launch_bounds__(256) void vq_prep(const float* __restrict__ cb,
                                               float* __restrict__ sc,
                                               float* __restrict__ losses) {
#pragma clang fp contract(off)
  {
    int k = blockIdx.x * 256 + threadIdx.x;   // grid 2*256 = 512
    const float* c = cb + (size_t)k * ND;
    float q[ND];
#pragma unroll
    for (int d = 0; d < ND; ++d) q[d] = c[d] * c[d];
    float r[8];
#pragma unroll
    for (int j = 0; j < 8; ++j) r[j] = q[j];
#pragma unroll
    for (int i = 8; i < ND; i += 8)
#pragma unroll
      for (int j = 0; j < 8; ++j) r[j] += q[i + j];
    float res = ((r[0] + r[1]) + (r[2] + r[3])) + ((r[4] + r[5]) + (r[6] + r[7]));
    sc[k] = res;
    if (k < 2) losses[k] = 0.f;
  }
}

// ---------------------------------------------------------------------------
// Main: 128 pixels/block, 256 threads, 8x8 register tile (was 4x4).
// R10 theory: prior kernel was LDS-issue-bound (~430k cyc/CU = 179us at
// ~11.5 cyc/ds_read_b128; FMA floor is only 54.6us). 8x8 tile halves LDS
// reads per FMA: per dq-step 16 ds_read_b128 feed 256 FMAs (was 8 per 64).
// Wave wv owns pixels {wv*32 + i*4 + r}, i=0..7; lane (r=lane&3, c=lane>>2)
// computes those 8 pixels x 8 codes {j*16+c} of the 128-code LDS chunk.
// LDS: lx 34.8KB + lcb 34.8KB + misc = ~71KB/block; 2 blocks/CU = 145KB.
// Numerics bit-identical to passing R2/R5/R7/R9: per-(n,k) sequential fp32
// FMA chain d=0..63 (dq ascending, xyzw within quad); d2 = fl(fl(Sx -
// fl(2M)) + Sc); Sx numpy pairwise-8; within-lane candidates ascend in code
// (j*16+c, chunks ascending) + strict '<'; cross-lane lexicographic
// (val,idx) min => lowest index wins ties = np.argmin.
// ---------------------------------------------------------------------------
__global__ __launch_bounds__(256, 2) void vq_main(const float* __restrict__ x,
                                                  const float* __restrict__ cb,
                                                  const float* __restrict__ sc,
                                                  float* __restrict__ out,
                                                  float* __restrict__ idx_out,
                                                  float* __restrict__ losses) {
#pragma clang fp contract(off)
  {
    __shared__ float lx[128 * XS];    // 34.8 KB x tile [pixel][d]
    __shared__ float lcb[128 * CS];   // 34.8 KB 128-code chunk [code][d]
    __shared__ float lsc[NK];         // 2 KB
    __shared__ float sxb[128];        // per-pixel Sx
    __shared__ int   shw[128];        // winning code per pixel
    __shared__ float red[4];

    const int tid = threadIdx.x;
    const int wv = __builtin_amdgcn_readfirstlane(tid >> 6);  // wave id
    const int lane = tid & 63;
    const int r = lane & 3;           // pixel row (within wave's 32)
    const int c = lane >> 2;          // code col
    const int g0 = blockIdx.x * 128;
    const int b = g0 >> 12;
    const int hw0 = g0 & 4095;
    const float* xbase = x + (size_t)b * (ND * NHW) + hw0;

    // ---- Stage x tile: thread covers pixel ph, dims [dh, dh+32).
    // waves 0,1 -> pixels 0..63 (dims 0-31 / 32-63); waves 2,3 -> 64..127.
    {
      const int ph = (tid & 63) + ((tid >> 7) << 6);
      const int dh = (tid & 64) ? 32 : 0;
#pragma unroll
      for (int j2 = 0; j2 < 8; ++j2) {
        const int d = dh + j2 * 4;
        float4 q;
        q.x = xbase[(size_t)(d + 0) * NHW + ph];
        q.y = xbase[(size_t)(d + 1) * NHW + ph];
        q.z = xbase[(size_t)(d + 2) * NHW + ph];
        q.w = xbase[(size_t)(d + 3) * NHW + ph];
        *(float4*)&lx[ph * XS + d] = q;
      }
    }
    // sc -> LDS (2 floats/thread).
    *(float2*)&lsc[tid * 2] = ((const float2*)sc)[tid];

    // ---- Prefetch chunk 0 to regs: thread t holds code t>>1, half t&1,
    // 8 quads = cb_f4[t*8 + j] (fully contiguous & coalesced).
    const int kk = tid >> 1, hh = tid & 1;
    float4 pf[8];
    {
      const float4* src = (const float4*)cb + (size_t)tid * 8;
#pragma unroll
      for (int j2 = 0; j2 < 8; ++j2) pf[j2] = src[j2];
    }

    float m1[8], Sxr[8];
    int i1[8];
#pragma unroll
    for (int i = 0; i < 8; ++i) { m1[i] = 3.0e38f; i1[i] = 0; }

    const int px0 = wv * 32 + r;      // pixels px0 + {0,4,...,28}

    for (int g = 0; g < 4; ++g) {
      __syncthreads();                 // prev chunk fully consumed
      {                                // regs -> LDS chunk buffer
        float* dst = &lcb[kk * CS + hh * 32];
#pragma unroll
        for (int j2 = 0; j2 < 8; ++j2) *(float4*)&dst[j2 * 4] = pf[j2];
      }
      if (g == 0 && tid < 128) {
        // Sx for pixel `tid`: rounded squares, pairwise-8 (bitwise = R2).
        const int pp = tid;
        float rr[8];
        float4 q0 = *(const float4*)&lx[pp * XS + 0];
        float4 q1 = *(const float4*)&lx[pp * XS + 4];
        rr[0] = q0.x * q0.x; rr[1] = q0.y * q0.y; rr[2] = q0.z * q0.z; rr[3] = q0.w * q0.w;
        rr[4] = q1.x * q1.x; rr[5] = q1.y * q1.y; rr[6] = q1.z * q1.z; rr[7] = q1.w * q1.w;
#pragma unroll
        for (int i = 2; i < 16; i += 2) {
          float4 a = *(const float4*)&lx[pp * XS + i * 4];
          float4 e = *(const float4*)&lx[pp * XS + i * 4 + 4];
          rr[0] += a.x * a.x; rr[1] += a.y * a.y; rr[2] += a.z * a.z; rr[3] += a.w * a.w;
          rr[4] += e.x * e.x; rr[5] += e.y * e.y; rr[6] += e.z * e.z; rr[7] += e.w * e.w;
        }
        sxb[pp] = ((rr[0] + rr[1]) + (rr[2] + rr[3])) + ((rr[4] + rr[5]) + (rr[6] + rr[7]));
      }
      __syncthreads();                 // chunk (and Sx) visible
      if (g < 3) {                     // prefetch next chunk
        const float4* src = (const float4*)(cb + (size_t)(g + 1) * 128 * ND) + (size_t)tid * 8;
#pragma unroll
        for (int j2 = 0; j2 < 8; ++j2) pf[j2] = src[j2];
      }
      if (g == 0) {                    // hoist Sx into regs once
#pragma unroll
        for (int i = 0; i < 8; ++i) Sxr[i] = sxb[px0 + 4 * i];
      }

      // ---- Register-tiled GEMM: this wave's 8 pixel-rows x 8 code-cols.
      float acc[8][8];
#pragma unroll
      for (int j = 0; j < 8; ++j)
#pragma unroll
        for (int i = 0; i < 8; ++i) acc[j][i] = 0.f;

#pragma unroll 4
      for (int dq = 0; dq < 16; ++dq) {
        float4 xq[8], cq[8];
#pragma unroll
        for (int i = 0; i < 8; ++i)
          xq[i] = *(const float4*)&lx[(px0 + 4 * i) * XS + dq * 4];
#pragma unroll
        for (int j = 0; j < 8; ++j)
          cq[j] = *(const float4*)&lcb[(j * 16 + c) * CS + dq * 4];
#pragma unroll
        for (int j = 0; j < 8; ++j)
#pragma unroll
          for (int i = 0; i < 8; ++i) {
            float a = acc[j][i];
            a = __builtin_fmaf(cq[j].x, xq[i].x, a);
            a = __builtin_fmaf(cq[j].y, xq[i].y, a);
            a = __builtin_fmaf(cq[j].z, xq[i].z, a);
            a = __builtin_fmaf(cq[j].w, xq[i].w, a);
            acc[j][i] = a;
          }
      }

      // ---- Combine + running argmin (codes ascend: j then later chunks).
      const int kb = g * 128;
#pragma unroll
      for (int j = 0; j < 8; ++j) {
        const float sj = lsc[kb + j * 16 + c];
        const int code = kb + j * 16 + c;
#pragma unroll
        for (int i = 0; i < 8; ++i) {
          const float d2 = (Sxr[i] - 2.0f * acc[j][i]) + sj;
          if (d2 < m1[i]) { m1[i] = d2; i1[i] = code; }
        }
      }
    }

    // ---- Cross-lane argmin per pixel: reduce over the 16 cols (lane bits
    // 2..5); lexicographic (val, idx) => exact np.argmin tie-breaking.
#pragma unroll
    for (int i = 0; i < 8; ++i) {
      float m = m1[i];
      int ii = i1[i];
#pragma unroll
      for (int s = 4; s < 64; s <<= 1) {
        const float om = __shfl_xor(m, s, 64);
        const int oi = __shfl_xor(ii, s, 64);
        if (om < m || (om == m && oi < ii)) { m = om; ii = oi; }
      }
      if (c == 0) {
        const int px = wv * 32 + i * 4 + r;   // same pixel the GEMM computed
        shw[px] = ii;
        idx_out[g0 + px] = (float)ii;
      }
    }
    __syncthreads();

    // ---- Epilogue: wave wv writes dims [wv*16,+16) for pixels lane, lane+64.
    float lossp = 0.f;
    float* op = out + (size_t)b * (ND * NHW) + hw0;
#pragma unroll
    for (int h = 0; h < 2; ++h) {
      const int pp = lane + h * 64;
      const int widx = shw[pp];
      const float* qrow = cb + (size_t)widx * ND;
#pragma unroll
      for (int j2 = 0; j2 < 4; ++j2) {
        const int d = wv * 16 + j2 * 4;
        const float4 q = *(const float4*)(qrow + d);
        const float4 xq = *(const float4*)&lx[pp * XS + d];
        float e;
        e = xq.x - q.x; lossp = __builtin_fmaf(e, e, lossp); op[(size_t)(d + 0) * NHW + pp] = q.x;
        e = xq.y - q.y; lossp = __builtin_fmaf(e, e, lossp); op[(size_t)(d + 1) * NHW + pp] = q.y;
        e = xq.z - q.z; lossp = __builtin_fmaf(e, e, lossp); op[(size_t)(d + 2) * NHW + pp] = q.z;
        e = xq.w - q.w; lossp = __builtin_fmaf(e, e, lossp); op[(size_t)(d + 3) * NHW + pp] = q.w;
      }
    }
#pragma unroll
    for (int off = 32; off; off >>= 1) lossp += __shfl_down(lossp, off);
    if (lane == 0) red[wv] = lossp;
    __syncthreads();
    if (tid == 0) {
      float t = (red[0] + red[1] + red[2] + red[3]) * (1.f / 8388608.f);
      atomicAdd(losses + 0, t);   // dictionary_loss
      atomicAdd(losses + 1, t);   // commitment_loss (identical forward value)
    }
  }
}

extern "C" void kernel_launch(void* const* d_in, const int* in_sizes, int n_in,
                              void* d_out, int out_size, void* d_ws, size_t ws_size,
                              hipStream_t stream) {
  const float* x  = (const float*)d_in[0];   // [32,64,64,64] fp32
  const float* cb = (const float*)d_in[1];   // [512,64] fp32
  float* out     = (float*)d_out;            // quantized [B,D,H,W]
  float* idx_out = out + OUT_ELEMS;          // indices (as fp32) [B,H,W]
  float* losses  = idx_out + NPIX;           // 2 scalars
  float* sc      = (float*)d_ws;             // 512 floats scratch

  vq_prep<<<2, 256, 0, stream>>>(cb, sc, losses);
  vq_main<<<NPIX / 128, 256, 0, stream>>>(x, cb, sc, out, idx_out, losses);
}